// Round 11
// baseline (90.606 us; speedup 1.0000x reference)
//
#include <hip/hip_runtime.h>
#include <cstdint>

typedef __attribute__((ext_vector_type(8))) short short8;
typedef __attribute__((ext_vector_type(4))) float f32x4;

__device__ inline unsigned short f2bf(float f){
  union { float f; uint32_t u; } v; v.f = f;
  uint32_t r = v.u + 0x7FFFu + ((v.u >> 16) & 1u);
  return (unsigned short)(r >> 16);
}

#define GLL(gp, lp) __builtin_amdgcn_global_load_lds(              \
    (const __attribute__((address_space(1))) void*)(gp),           \
    (__attribute__((address_space(3))) void*)(lp), 16, 0, 0)

// ---------------- kernel 1: weight conversions --------------------------
__global__ __launch_bounds__(256) void kconv(const float* __restrict__ W,
                                             const float* __restrict__ A,
                                             const float* __restrict__ Bm,
                                             unsigned short* __restrict__ Wb,
                                             unsigned short* __restrict__ BTt,
                                             unsigned short* __restrict__ W2b){
  int i = blockIdx.x * 256 + threadIdx.x;
  Wb[i] = f2bf(W[i]);
  if (i < 32768){
    int o = i >> 5, c = i & 31;
    BTt[i] = f2bf(Bm[(size_t)c*1024 + o]);
    int n = i >> 10, d = i & 1023;
    W2b[i] = f2bf(A[(((size_t)(n>>2))*1024 + d)*4 + (n&3)]);
  }
}

// ---------------- kernel 2: fused x->bf16 + router(f32) + h(MFMA) -------
// 512 blocks x 256 thr. Wave pair (tg, k-half): 16 tokens, 512 k each.
// Per ks-step: coalesced f32 x load (lane = row*4+chunk), convert+store xb,
// in-register shuffle bf16 to MFMA layout, h-MFMA vs W2b (L2), router
// partials in f32 from pre-shuffle values. Epilogue: LDS reduce across
// k-halves, f32 softmax/top2/renorm, HG = h*gate -> global.
__global__ __launch_bounds__(256) void klxh(const float* __restrict__ x,
                                            const float* __restrict__ Wr,
                                            const unsigned short* __restrict__ W2b,
                                            unsigned short* __restrict__ xb,
                                            unsigned short* __restrict__ HG){
  __shared__ float xch[4][64][8];    // h partials (8KB)
  __shared__ float plog[4][16][8];   // logit partials (2KB)
  __shared__ float gl[32][8];        // gates (1KB)
  const int tid  = threadIdx.x;
  const int lane = tid & 63;
  const int wid  = tid >> 6;
  const int tg   = wid >> 1;              // token-group 0/1
  const int khf  = wid & 1;               // k-half 0/1
  const int tok0 = blockIdx.x*32 + tg*16;
  const int r    = lane >> 2;             // loader row 0..15
  const int ch   = lane & 3;              // loader k-chunk 0..3
  const int lrow = lane & 15;             // mfma row
  const int q8   = lane >> 4;             // mfma k-sub 0..3
  const int srcl = ((lane & 15) << 2) | (lane >> 4);

  const float*    xrow  = x  + (size_t)(tok0 + r)*1024;
  unsigned short* xbrow = xb + (size_t)(tok0 + r)*1024;
  const unsigned short* b0p = W2b + (size_t)lrow*1024;
  const unsigned short* b1p = W2b + (size_t)(16 + lrow)*1024;

  f32x4 acc0 = {0.f,0.f,0.f,0.f}, acc1 = {0.f,0.f,0.f,0.f};
  float p[8] = {0.f,0.f,0.f,0.f,0.f,0.f,0.f,0.f};

  #pragma unroll 2
  for (int t=0; t<16; t++){
    const int k0 = (khf*16 + t)*32 + ch*8;      // f32/bf16 element index
    float4 v0 = *(const float4*)(xrow + k0);
    float4 v1 = *(const float4*)(xrow + k0 + 4);
    union { short8 s; int i[4]; } cv;
    cv.i[0] = (int)f2bf(v0.x) | ((int)f2bf(v0.y) << 16);
    cv.i[1] = (int)f2bf(v0.z) | ((int)f2bf(v0.w) << 16);
    cv.i[2] = (int)f2bf(v1.x) | ((int)f2bf(v1.y) << 16);
    cv.i[3] = (int)f2bf(v1.z) | ((int)f2bf(v1.w) << 16);
    *(int4*)(xbrow + k0) = *(int4*)cv.i;        // 4 lanes -> one 64B line
    // shuffle bf16 into MFMA layout: lane needs row (lane&15), chunk (lane>>4)
    union { short8 s; int i[4]; } av;
    #pragma unroll
    for (int u=0; u<4; u++) av.i[u] = __shfl(cv.i[u], srcl, 64);
    const int kb = (khf*16 + t)*32 + q8*8;
    short8 bv0 = *(const short8*)(b0p + kb);
    short8 bv1 = *(const short8*)(b1p + kb);
    acc0 = __builtin_amdgcn_mfma_f32_16x16x32_bf16(av.s, bv0, acc0, 0, 0, 0);
    acc1 = __builtin_amdgcn_mfma_f32_16x16x32_bf16(av.s, bv1, acc1, 0, 0, 0);
    // router partials in f32 (pre-shuffle values, exact selection math)
    #pragma unroll
    for (int e=0; e<8; e++){
      const float* wre = Wr + (size_t)e*1024 + k0;
      float4 w0 = *(const float4*)(wre);
      float4 w1 = *(const float4*)(wre + 4);
      p[e] += v0.x*w0.x + v0.y*w0.y + v0.z*w0.z + v0.w*w0.w
            + v1.x*w1.x + v1.y*w1.y + v1.z*w1.z + v1.w*w1.w;
    }
  }

  // reduce router partials over the 4 chunk-lanes of each row
  #pragma unroll
  for (int off=1; off<4; off<<=1){
    #pragma unroll
    for (int e=0; e<8; e++) p[e] += __shfl_xor(p[e], off, 64);
  }
  if (ch == 0){
    #pragma unroll
    for (int e=0; e<8; e++) plog[wid][r][e] = p[e];
  }
  #pragma unroll
  for (int j=0; j<4; j++){
    xch[wid][lane][j]   = acc0[j];
    xch[wid][lane][4+j] = acc1[j];
  }
  __syncthreads();

  if (khf == 0 && lane < 16){
    float lg[8];
    #pragma unroll
    for (int e=0; e<8; e++) lg[e] = plog[wid][lane][e] + plog[wid+1][lane][e];
    float mx = lg[0];
    #pragma unroll
    for (int e=1; e<8; e++) mx = fmaxf(mx, lg[e]);
    float ex[8], s2 = 0.f;
    #pragma unroll
    for (int e=0; e<8; e++){ ex[e] = __expf(lg[e]-mx); s2 += ex[e]; }
    int i1 = 0; float v1 = ex[0];
    #pragma unroll
    for (int e=1; e<8; e++) if (ex[e] > v1){ v1 = ex[e]; i1 = e; }
    int i2 = -1; float v2 = -1.f;
    #pragma unroll
    for (int e=0; e<8; e++) if (e != i1 && ex[e] > v2){ v2 = ex[e]; i2 = e; }
    float g1 = v1/s2, g2 = v2/s2;
    float rs = 1.f/(g1 + g2 + 1e-6f);
    #pragma unroll
    for (int e=0; e<8; e++)
      gl[tg*16 + lane][e] = (e==i1 ? g1 : (e==i2 ? g2 : 0.f)) * rs;
  }
  __syncthreads();

  if (khf == 0){
    float h0[4], h1[4];
    #pragma unroll
    for (int j=0; j<4; j++){
      h0[j] = xch[wid][lane][j]   + xch[wid+1][lane][j];
      h1[j] = xch[wid][lane][4+j] + xch[wid+1][lane][4+j];
    }
    #pragma unroll
    for (int j=0; j<4; j++){
      int tl = tg*16 + q8*4 + j;                     // local token
      size_t tgl = (size_t)blockIdx.x*32 + tl;       // global token
      float g0 = gl[tl][lrow>>2];
      float g1 = gl[tl][4 + (lrow>>2)];
      HG[tgl*32 + lrow]      = f2bf(h0[j]*g0);
      HG[tgl*32 + 16 + lrow] = f2bf(h1[j]*g1);
    }
  }
}

// ---------------- kernel 3: 128x128 m97-style GEMM + LoRA ---------------
// Proven best (r8/r10): 4 waves, BK=64, single-buffered 32KB LDS, 2-barrier
// loop, compiler scheduling, 4 blocks/CU, swizzle ^(row&7)<<4, LoRA
// epilogue fragments direct from global (L2-hot).
__global__ __launch_bounds__(256, 4) void kgemm7(const unsigned short* __restrict__ xb,
                                                 const unsigned short* __restrict__ Wb,
                                                 const unsigned short* __restrict__ BTt,
                                                 const unsigned short* __restrict__ HG,
                                                 const float* __restrict__ bias,
                                                 float* __restrict__ out){
  __shared__ __attribute__((aligned(128))) char lds[32768];  // A@0, B@16K
  const int tid  = threadIdx.x;
  const int lane = tid & 63;
  const int w    = tid >> 6;
  const int mblk = blockIdx.x & 127;      // same-mblk blocks -> same XCD
  const int nblk = blockIdx.x >> 7;
  const int m0 = mblk << 7, n0 = nblk << 7;
  const int wm = w >> 1, wn = w & 1;
  const int lrow = lane & 15;
  const int q    = lane >> 4;

  const int rowL = lane >> 3;
  const int colb = ((lane & 7) ^ rowL) << 4;
  const int rb   = w * 32;
  const char* Ag = (const char*)xb + ((size_t)(m0 + rb + rowL) << 11) + colb;
  const char* Bg = (const char*)Wb + ((size_t)(n0 + rb + rowL) << 11) + colb;
  char* Ad = lds +         rb*128 + lane*16;
  char* Bd = lds + 16384 + rb*128 + lane*16;

  int offA[4][2], offB[4][2];
  #pragma unroll
  for (int f=0; f<4; f++){
    int ra  = wm*64 + f*16 + lrow;
    int rbn = wn*64 + f*16 + lrow;
    #pragma unroll
    for (int kk=0; kk<2; kk++){
      offA[f][kk] =         ra*128  + ((((kk*4+q) ^ (ra  & 7)) << 4));
      offB[f][kk] = 16384 + rbn*128 + ((((kk*4+q) ^ (rbn & 7)) << 4));
    }
  }

  f32x4 acc[4][4];
  #pragma unroll
  for (int a2=0;a2<4;a2++)
    #pragma unroll
    for (int b2=0;b2<4;b2++) acc[a2][b2] = (f32x4){0.f,0.f,0.f,0.f};

  #pragma unroll 1
  for (int t = 0; t < 16; ++t){
    __syncthreads();
    #pragma unroll
    for (int i=0;i<4;i++) GLL(Ag + (size_t)i*16384 + t*128, Ad + i*1024);
    #pragma unroll
    for (int i=0;i<4;i++) GLL(Bg + (size_t)i*16384 + t*128, Bd + i*1024);
    __syncthreads();
    #pragma unroll
    for (int kk=0; kk<2; kk++){
      short8 a[4], b[4];
      #pragma unroll
      for (int f=0; f<4; f++){
        a[f] = *(const short8*)(lds + offA[f][kk]);
        b[f] = *(const short8*)(lds + offB[f][kk]);
      }
      #pragma unroll
      for (int fm=0;fm<4;fm++)
        #pragma unroll
        for (int fn=0;fn<4;fn++)
          acc[fm][fn] = __builtin_amdgcn_mfma_f32_16x16x32_bf16(a[fm], b[fn], acc[fm][fn], 0, 0, 0);
    }
  }

  // ---- LoRA K=32 step: fragments direct from global (L2-hot) ----
  {
    short8 ha[4], hb[4];
    #pragma unroll
    for (int f=0; f<4; f++){
      ha[f] = *(const short8*)(HG  + (size_t)(m0 + wm*64 + f*16 + lrow)*32 + q*8);
      hb[f] = *(const short8*)(BTt + (size_t)(n0 + wn*64 + f*16 + lrow)*32 + q*8);
    }
    #pragma unroll
    for (int fm=0;fm<4;fm++)
      #pragma unroll
      for (int fn=0;fn<4;fn++)
        acc[fm][fn] = __builtin_amdgcn_mfma_f32_16x16x32_bf16(ha[fm], hb[fn], acc[fm][fn], 0, 0, 0);
  }

  // ---- store: + bias ----
  #pragma unroll
  for (int fn=0;fn<4;fn++){
    int col = n0 + wn*64 + fn*16 + lrow;
    float bv = bias[col];
    #pragma unroll
    for (int fm=0;fm<4;fm++){
      int rbo = m0 + wm*64 + fm*16 + q*4;
      #pragma unroll
      for (int j=0;j<4;j++)
        out[(size_t)(rbo+j)*1024 + col] = acc[fm][fn][j] + bv;
    }
  }
}

// ---------------- host ---------------------------------------------------
extern "C" void kernel_launch(void* const* d_in, const int* in_sizes, int n_in,
                              void* d_out, int out_size, void* d_ws, size_t ws_size,
                              hipStream_t stream){
  const float* x  = (const float*)d_in[0];
  const float* W  = (const float*)d_in[1];
  const float* bb = (const float*)d_in[2];
  const float* Wr = (const float*)d_in[3];
  const float* A  = (const float*)d_in[4];
  const float* Bm = (const float*)d_in[5];
  float* out = (float*)d_out;
  char* ws = (char*)d_ws;

  // ws layout: Wb 2MB | BTt 64KB | W2b 64KB | HG 1MB | xb 32MB
  unsigned short* Wb   = (unsigned short*)(ws + 0);
  unsigned short* BTt  = (unsigned short*)(ws + 2097152);
  unsigned short* W2b  = (unsigned short*)(ws + 2162688);
  unsigned short* HG   = (unsigned short*)(ws + 2228224);
  unsigned short* xb   = (unsigned short*)(ws + 3276800);

  kconv<<<4096, 256, 0, stream>>>(W, A, Bm, Wb, BTt, W2b);
  klxh<<<512, 256, 0, stream>>>(x, Wr, W2b, xb, HG);
  kgemm7<<<1024, 256, 0, stream>>>(xb, Wb, BTt, HG, bb, out);
}